// Round 18
// baseline (127.866 us; speedup 1.0000x reference)
//
#include <hip/hip_runtime.h>

#define MTOT (16 * 4096)   // 65536 queries
#define KDIM 256           // vector dim
#define CBSZ 1024          // codebook size

using half8  = _Float16 __attribute__((ext_vector_type(8)));
using f32x16 = float    __attribute__((ext_vector_type(16)));

// ---------------------------------------------------------------------------
// Kernel 1 (prep): codebook -> fragment-major fp16 hi/lo + squared norms.
// cbF layout (half8 units): [panel(32)][kc(16)][term(2)][lane(64)]
//   lane = g*32 + (c&31), holds cb[c][kc*16 + g*8 .. +8]
// ---------------------------------------------------------------------------
__global__ void vq_prep(const float* __restrict__ cb,
                        _Float16* __restrict__ cbF, float* __restrict__ hn) {
    const int flat = blockIdx.x * 256 + threadIdx.x;   // 32768 total
    const int c = flat >> 5;
    const int grp = flat & 31;
    const int kc = grp >> 1, g = grp & 1;
    const float* p = cb + (size_t)c * KDIM + grp * 8;
    float4 f0 = *reinterpret_cast<const float4*>(p);
    float4 f1 = *reinterpret_cast<const float4*>(p + 4);
    float fv[8] = {f0.x, f0.y, f0.z, f0.w, f1.x, f1.y, f1.z, f1.w};
    half8 h, l;
    float s = 0.0f;
    #pragma unroll
    for (int j = 0; j < 8; ++j) {
        h[j] = (_Float16)fv[j];
        l[j] = (_Float16)(fv[j] - (float)h[j]);
        s += fv[j] * fv[j];
    }
    const int pan = c >> 5, m = c & 31;
    const int lane = g * 32 + m;
    const size_t off = (((size_t)pan * 16 + kc) * 2 + 0) * 64 + lane;  // half8 units
    *reinterpret_cast<half8*>(cbF + off * 8) = h;
    *reinterpret_cast<half8*>(cbF + (off + 64) * 8) = l;               // term=1 (+64 half8)
    #pragma unroll
    for (int d = 16; d; d >>= 1) s += __shfl_xor(s, d);
    if (grp == 0) hn[c] = s;
}

// ---------------------------------------------------------------------------
// Kernel 2: MFMA distance GEMM + argmin + fused gather/loss.
// 512 threads, 64 queries/block, LDS 64 KB (qF only; scratch overlaid).
// R18 = R16 shell (validated) + R13's acc[2] 6-MFMA tile with R9's
// named-register distance-1 prefetch (validated pattern) on A (L2) and B
// (LDS): per-iter loads are issued one kc ahead, so MFMAs of iter k cover
// the latency of iter k+1's loads.  Arch live ~60 <= 64 cap (LB(512,4));
// + acc 32 AGPR -> ~96/wave -> 4 waves/SIMD, 2 blocks/CU (R13/R16 regime).
// Numerics: per-acc MFMA order hh, lh, hl; ascending codeword argmin;
// identical to the R10-R16 passing lineage (prefetch changes only schedule).
// ---------------------------------------------------------------------------
__global__ __launch_bounds__(512, 4)
void vq_main(const float* __restrict__ A,          // z_e [MTOT][KDIM] fp32
             const _Float16* __restrict__ cbF,     // fragment-major codebook
             const float* __restrict__ hn,         // [CBSZ] norms
             const float* __restrict__ cb,         // original codebook fp32
             float* __restrict__ out_idx_f,
             float* __restrict__ zq,
             float* __restrict__ part_s,           // [1024] per-block bv sums
             float* __restrict__ part_x2) {        // [1024*8] per-wave x^2 sums
    // qF layout (half8 units): [qg(2)][kc(16)][term(2)][slot(64)]
    __shared__ _Float16 qF[2 * 16 * 2 * 64 * 8];   // 64 KB exactly

    const int tid = threadIdx.x;
    const int qbase = blockIdx.x * 64;
    const int lane = tid & 63;
    const int wave = tid >> 6;

    // ---- stage queries: fp32 -> fp16 hi/lo fragments in LDS; accumulate x^2
    float xsq = 0.0f;
    #pragma unroll
    for (int it = 0; it < 4; ++it) {
        const int flat = it * 512 + tid;            // 2048 groups
        const int q = flat >> 5;                    // 0..63
        const int grp = flat & 31;
        const int kc = grp >> 1, g = grp & 1;
        const float* p = A + (size_t)(qbase + q) * KDIM + grp * 8;
        float4 f0 = *reinterpret_cast<const float4*>(p);
        float4 f1 = *reinterpret_cast<const float4*>(p + 4);
        float fv[8] = {f0.x, f0.y, f0.z, f0.w, f1.x, f1.y, f1.z, f1.w};
        half8 h, l;
        #pragma unroll
        for (int j = 0; j < 8; ++j) {
            h[j] = (_Float16)fv[j];
            l[j] = (_Float16)(fv[j] - (float)h[j]);
            xsq += fv[j] * fv[j];
        }
        const int qg = q >> 5;
        const int lw = g * 32 + (q & 31);
        const int sl = lw ^ (kc & 7);               // swizzled 16B slot
        _Float16* dst = qF + (((qg * 16 + kc) * 2 + 0) * 64 + sl) * 8;
        *reinterpret_cast<half8*>(dst) = h;
        *reinterpret_cast<half8*>(dst + 512) = l;   // term=1: +64 half8 = +512 halves
    }
    #pragma unroll
    for (int d = 32; d; d >>= 1) xsq += __shfl_xor(xsq, d);
    if (lane == 0) part_x2[blockIdx.x * 8 + wave] = xsq;
    __syncthreads();

    const int m31 = lane & 31;
    const int g = lane >> 5;

    float minv[2];
    int   mini[2];
    #pragma unroll
    for (int qg = 0; qg < 2; ++qg) { minv[qg] = 3.4e38f; mini[qg] = 0; }

    #pragma unroll 1
    for (int pi = 0; pi < 4; ++pi) {
        const int pan = wave * 4 + pi;              // one panel at a time

        f32x16 acc0 = (f32x16){};                   // [qg0]
        f32x16 acc1 = (f32x16){};                   // [qg1]

        // A-fragment address helper (half8 units)
        #define AFRAG(kc_, t_) \
            (*reinterpret_cast<const half8*>(cbF + ((((size_t)pan * 16 + (kc_)) * 2 + (t_)) * 64 + lane) * 8))
        #define BPTR(qg_, kc_, sl_) (qF + ((((qg_) * 16 + (kc_)) * 2 + 0) * 64 + (sl_)) * 8)

        // prologue: load kc=0 fragments (sl for kc=0 is lane^0 = lane)
        half8 Ah = AFRAG(0, 0);
        half8 Al = AFRAG(0, 1);
        const _Float16* q0p = BPTR(0, 0, lane);
        const _Float16* q1p = BPTR(1, 0, lane);
        half8 bh0 = *reinterpret_cast<const half8*>(q0p);
        half8 bl0 = *reinterpret_cast<const half8*>(q0p + 512);
        half8 bh1 = *reinterpret_cast<const half8*>(q1p);
        half8 bl1 = *reinterpret_cast<const half8*>(q1p + 512);

        #pragma unroll 4
        for (int kc = 0; kc < 16; ++kc) {
            // distance-1 prefetch (clamped, no branch)
            const int kn = (kc + 1 < 16) ? kc + 1 : 15;
            half8 nAh = AFRAG(kn, 0);
            half8 nAl = AFRAG(kn, 1);
            const int sln = lane ^ (kn & 7);
            const _Float16* nq0 = BPTR(0, kn, sln);
            const _Float16* nq1 = BPTR(1, kn, sln);
            half8 nbh0 = *reinterpret_cast<const half8*>(nq0);
            half8 nbl0 = *reinterpret_cast<const half8*>(nq0 + 512);
            half8 nbh1 = *reinterpret_cast<const half8*>(nq1);
            half8 nbl1 = *reinterpret_cast<const half8*>(nq1 + 512);

            // per-acc order: hh, lh, hl (numerics identical to R8-R16)
            acc0 = __builtin_amdgcn_mfma_f32_32x32x16_f16(Ah, bh0, acc0, 0, 0, 0);
            acc1 = __builtin_amdgcn_mfma_f32_32x32x16_f16(Ah, bh1, acc1, 0, 0, 0);
            acc0 = __builtin_amdgcn_mfma_f32_32x32x16_f16(Al, bh0, acc0, 0, 0, 0);
            acc1 = __builtin_amdgcn_mfma_f32_32x32x16_f16(Al, bh1, acc1, 0, 0, 0);
            acc0 = __builtin_amdgcn_mfma_f32_32x32x16_f16(Ah, bl0, acc0, 0, 0, 0);
            acc1 = __builtin_amdgcn_mfma_f32_32x32x16_f16(Ah, bl1, acc1, 0, 0, 0);

            // rotate
            Ah = nAh; Al = nAl;
            bh0 = nbh0; bl0 = nbl0; bh1 = nbh1; bl1 = nbl1;
        }
        #undef AFRAG
        #undef BPTR

        // epilogue: surrogate distance + running argmin (ascending codeword).
        // hn[] read from global (broadcast addresses, L1-hot).
        const int cwb = pan * 32 + 4 * g;
        #pragma unroll
        for (int r = 0; r < 16; ++r) {
            const int cw = cwb + (r & 3) + 8 * (r >> 2);
            const float hc = hn[cw];
            float s0 = fmaf(-2.0f, acc0[r], hc);
            if (s0 < minv[0]) { minv[0] = s0; mini[0] = cw; }
            float s1 = fmaf(-2.0f, acc1[r], hc);
            if (s1 < minv[1]) { minv[1] = s1; mini[1] = cw; }
        }
    }

    // combine the two g-halves in-register (tie -> lower index)
    #pragma unroll
    for (int qg = 0; qg < 2; ++qg) {
        float ov = __shfl_xor(minv[qg], 32);
        int oi = __shfl_xor(mini[qg], 32);
        if (ov < minv[qg] || (ov == minv[qg] && oi < mini[qg])) {
            minv[qg] = ov; mini[qg] = oi;
        }
    }

    // qF is now dead -> overlay cross-wave scratch + final indices on it
    __syncthreads();
    float* sm   = reinterpret_cast<float*>(qF);          // [8][64]
    int*   si   = reinterpret_cast<int*>(qF) + 512;      // [8][64]
    int*   fidx = reinterpret_cast<int*>(qF) + 1024;     // [64]
    if (g == 0) {
        #pragma unroll
        for (int qg = 0; qg < 2; ++qg) {
            sm[wave * 64 + qg * 32 + m31] = minv[qg];
            si[wave * 64 + qg * 32 + m31] = mini[qg];
        }
    }
    __syncthreads();

    // cross-wave reduce (wave order = ascending codeword blocks), then
    // block loss partial = sum of selected surrogate distances.
    if (tid < 64) {
        float bv = sm[tid]; int bi = si[tid];
        #pragma unroll
        for (int w = 1; w < 8; ++w) {
            float v = sm[w * 64 + tid]; int ii = si[w * 64 + tid];
            if (v < bv || (v == bv && ii < bi)) { bv = v; bi = ii; }
        }
        out_idx_f[qbase + tid] = (float)bi;
        fidx[tid] = bi;
        float vs = bv;
        #pragma unroll
        for (int d = 32; d; d >>= 1) vs += __shfl_xor(vs, d);
        if (tid == 0) part_s[blockIdx.x] = vs;
    }
    __syncthreads();

    // fused gather: z_q rows for this block's 64 queries (coalesced, cb L2-hot)
    const float4* cb4 = reinterpret_cast<const float4*>(cb);
    float4* zq4 = reinterpret_cast<float4*>(zq) + (size_t)qbase * 64;
    #pragma unroll
    for (int it = 0; it < 8; ++it) {
        const int j = it * 512 + tid;               // 4096 float4 units
        const int q = j >> 6, seg = j & 63;
        const int cw = fidx[q];
        zq4[j] = cb4[(size_t)cw * 64 + seg];
    }
}

// ---------------------------------------------------------------------------
// Kernel 3: reduce partials -> loss = (sum_s + sum_x2) / (B*N*D)
// ---------------------------------------------------------------------------
__global__ void vq_finish(const float* __restrict__ part_s,
                          const float* __restrict__ part_x2,
                          float* __restrict__ out_loss) {
    float s = 0.0f;
    for (int i = threadIdx.x; i < 1024; i += 256) s += part_s[i];
    for (int i = threadIdx.x; i < 8192; i += 256) s += part_x2[i];
    #pragma unroll
    for (int d = 32; d; d >>= 1) s += __shfl_xor(s, d);
    __shared__ float ps[4];
    if ((threadIdx.x & 63) == 0) ps[threadIdx.x >> 6] = s;
    __syncthreads();
    if (threadIdx.x == 0)
        *out_loss = (ps[0] + ps[1] + ps[2] + ps[3]) * (1.0f / 16777216.0f);
}

extern "C" void kernel_launch(void* const* d_in, const int* in_sizes, int n_in,
                              void* d_out, int out_size, void* d_ws, size_t ws_size,
                              hipStream_t stream) {
    const float* z_e = (const float*)d_in[0];
    const float* cb  = (const float*)d_in[1];

    float* out   = (float*)d_out;
    float* zq    = out;
    float* oidx  = out + (size_t)MTOT * KDIM;
    float* oloss = out + (size_t)MTOT * KDIM + MTOT;

    char* ws = (char*)d_ws;
    _Float16* cbF  = (_Float16*)ws;                              // 1 MB
    float* hn      = (float*)(ws + 1024 * 1024);                 // 4 KB
    float* part_s  = (float*)(ws + 1024 * 1024 + 4096);          // 4 KB
    float* part_x2 = (float*)(ws + 1024 * 1024 + 8192);          // 32 KB

    vq_prep<<<128, 256, 0, stream>>>(cb, cbF, hn);
    vq_main<<<MTOT / 64, 512, 0, stream>>>(z_e, cbF, hn, cb, oidx, zq,
                                           part_s, part_x2);
    vq_finish<<<1, 256, 0, stream>>>(part_s, part_x2, oloss);
}

// Round 19
// 126.574 us; speedup vs baseline: 1.0102x; 1.0102x over previous
//
#include <hip/hip_runtime.h>

#define MTOT (16 * 4096)   // 65536 queries
#define KDIM 256           // vector dim
#define CBSZ 1024          // codebook size

using half8  = _Float16 __attribute__((ext_vector_type(8)));
using f32x16 = float    __attribute__((ext_vector_type(16)));

// ---------------------------------------------------------------------------
// Kernel 1 (prep): codebook -> fragment-major fp16 hi/lo + squared norms.
// cbF layout (half8 units): [panel(32)][kc(16)][term(2)][lane(64)]
//   lane = g*32 + (c&31), holds cb[c][kc*16 + g*8 .. +8]
// ---------------------------------------------------------------------------
__global__ void vq_prep(const float* __restrict__ cb,
                        _Float16* __restrict__ cbF, float* __restrict__ hn) {
    const int flat = blockIdx.x * 256 + threadIdx.x;   // 32768 total
    const int c = flat >> 5;
    const int grp = flat & 31;
    const int kc = grp >> 1, g = grp & 1;
    const float* p = cb + (size_t)c * KDIM + grp * 8;
    float4 f0 = *reinterpret_cast<const float4*>(p);
    float4 f1 = *reinterpret_cast<const float4*>(p + 4);
    float fv[8] = {f0.x, f0.y, f0.z, f0.w, f1.x, f1.y, f1.z, f1.w};
    half8 h, l;
    float s = 0.0f;
    #pragma unroll
    for (int j = 0; j < 8; ++j) {
        h[j] = (_Float16)fv[j];
        l[j] = (_Float16)(fv[j] - (float)h[j]);
        s += fv[j] * fv[j];
    }
    const int pan = c >> 5, m = c & 31;
    const int lane = g * 32 + m;
    const size_t off = (((size_t)pan * 16 + kc) * 2 + 0) * 64 + lane;  // half8 units
    *reinterpret_cast<half8*>(cbF + off * 8) = h;
    *reinterpret_cast<half8*>(cbF + (off + 64) * 8) = l;               // term=1 (+64 half8)
    #pragma unroll
    for (int d = 16; d; d >>= 1) s += __shfl_xor(s, d);
    if (grp == 0) hn[c] = s;
}

// ---------------------------------------------------------------------------
// Kernel 2: MFMA distance GEMM + argmin + fused gather/loss.
// 512 threads, 64 queries/block, LDS 64 KB (qF only; scratch overlaid).
// R19 = R18 (validated: R16 shell + acc[2] tile + distance-1 named-register
// prefetch) + s_setprio(1) around the MFMA cluster (R14-validated pattern;
// T5 mechanism applies: barrier-free main loop -> waves at different phases,
// scheduler can favor the MFMA-issuing wave).
// Register budget: arch ~52-60 <= 64 cap (LB(512,4)) + acc 32 AGPR
// -> ~90/wave -> 4 waves/SIMD, 2 blocks/CU (R13/R16/R18 regime).
// Numerics: per-acc MFMA order hh, lh, hl; ascending codeword argmin;
// identical to the R10-R18 passing lineage.
// ---------------------------------------------------------------------------
__global__ __launch_bounds__(512, 4)
void vq_main(const float* __restrict__ A,          // z_e [MTOT][KDIM] fp32
             const _Float16* __restrict__ cbF,     // fragment-major codebook
             const float* __restrict__ hn,         // [CBSZ] norms
             const float* __restrict__ cb,         // original codebook fp32
             float* __restrict__ out_idx_f,
             float* __restrict__ zq,
             float* __restrict__ part_s,           // [1024] per-block bv sums
             float* __restrict__ part_x2) {        // [1024*8] per-wave x^2 sums
    // qF layout (half8 units): [qg(2)][kc(16)][term(2)][slot(64)]
    __shared__ _Float16 qF[2 * 16 * 2 * 64 * 8];   // 64 KB exactly

    const int tid = threadIdx.x;
    const int qbase = blockIdx.x * 64;
    const int lane = tid & 63;
    const int wave = tid >> 6;

    // ---- stage queries: fp32 -> fp16 hi/lo fragments in LDS; accumulate x^2
    float xsq = 0.0f;
    #pragma unroll
    for (int it = 0; it < 4; ++it) {
        const int flat = it * 512 + tid;            // 2048 groups
        const int q = flat >> 5;                    // 0..63
        const int grp = flat & 31;
        const int kc = grp >> 1, g = grp & 1;
        const float* p = A + (size_t)(qbase + q) * KDIM + grp * 8;
        float4 f0 = *reinterpret_cast<const float4*>(p);
        float4 f1 = *reinterpret_cast<const float4*>(p + 4);
        float fv[8] = {f0.x, f0.y, f0.z, f0.w, f1.x, f1.y, f1.z, f1.w};
        half8 h, l;
        #pragma unroll
        for (int j = 0; j < 8; ++j) {
            h[j] = (_Float16)fv[j];
            l[j] = (_Float16)(fv[j] - (float)h[j]);
            xsq += fv[j] * fv[j];
        }
        const int qg = q >> 5;
        const int lw = g * 32 + (q & 31);
        const int sl = lw ^ (kc & 7);               // swizzled 16B slot
        _Float16* dst = qF + (((qg * 16 + kc) * 2 + 0) * 64 + sl) * 8;
        *reinterpret_cast<half8*>(dst) = h;
        *reinterpret_cast<half8*>(dst + 512) = l;   // term=1: +64 half8 = +512 halves
    }
    #pragma unroll
    for (int d = 32; d; d >>= 1) xsq += __shfl_xor(xsq, d);
    if (lane == 0) part_x2[blockIdx.x * 8 + wave] = xsq;
    __syncthreads();

    const int m31 = lane & 31;
    const int g = lane >> 5;

    float minv[2];
    int   mini[2];
    #pragma unroll
    for (int qg = 0; qg < 2; ++qg) { minv[qg] = 3.4e38f; mini[qg] = 0; }

    #pragma unroll 1
    for (int pi = 0; pi < 4; ++pi) {
        const int pan = wave * 4 + pi;              // one panel at a time

        f32x16 acc0 = (f32x16){};                   // [qg0]
        f32x16 acc1 = (f32x16){};                   // [qg1]

        // A-fragment address helper (half8 units)
        #define AFRAG(kc_, t_) \
            (*reinterpret_cast<const half8*>(cbF + ((((size_t)pan * 16 + (kc_)) * 2 + (t_)) * 64 + lane) * 8))
        #define BPTR(qg_, kc_, sl_) (qF + ((((qg_) * 16 + (kc_)) * 2 + 0) * 64 + (sl_)) * 8)

        // prologue: load kc=0 fragments (sl for kc=0 is lane^0 = lane)
        half8 Ah = AFRAG(0, 0);
        half8 Al = AFRAG(0, 1);
        const _Float16* q0p = BPTR(0, 0, lane);
        const _Float16* q1p = BPTR(1, 0, lane);
        half8 bh0 = *reinterpret_cast<const half8*>(q0p);
        half8 bl0 = *reinterpret_cast<const half8*>(q0p + 512);
        half8 bh1 = *reinterpret_cast<const half8*>(q1p);
        half8 bl1 = *reinterpret_cast<const half8*>(q1p + 512);

        #pragma unroll 4
        for (int kc = 0; kc < 16; ++kc) {
            // distance-1 prefetch (clamped, no branch)
            const int kn = (kc + 1 < 16) ? kc + 1 : 15;
            half8 nAh = AFRAG(kn, 0);
            half8 nAl = AFRAG(kn, 1);
            const int sln = lane ^ (kn & 7);
            const _Float16* nq0 = BPTR(0, kn, sln);
            const _Float16* nq1 = BPTR(1, kn, sln);
            half8 nbh0 = *reinterpret_cast<const half8*>(nq0);
            half8 nbl0 = *reinterpret_cast<const half8*>(nq0 + 512);
            half8 nbh1 = *reinterpret_cast<const half8*>(nq1);
            half8 nbl1 = *reinterpret_cast<const half8*>(nq1 + 512);

            // per-acc order: hh, lh, hl (numerics identical to R8-R18)
            __builtin_amdgcn_s_setprio(1);
            acc0 = __builtin_amdgcn_mfma_f32_32x32x16_f16(Ah, bh0, acc0, 0, 0, 0);
            acc1 = __builtin_amdgcn_mfma_f32_32x32x16_f16(Ah, bh1, acc1, 0, 0, 0);
            acc0 = __builtin_amdgcn_mfma_f32_32x32x16_f16(Al, bh0, acc0, 0, 0, 0);
            acc1 = __builtin_amdgcn_mfma_f32_32x32x16_f16(Al, bh1, acc1, 0, 0, 0);
            acc0 = __builtin_amdgcn_mfma_f32_32x32x16_f16(Ah, bl0, acc0, 0, 0, 0);
            acc1 = __builtin_amdgcn_mfma_f32_32x32x16_f16(Ah, bl1, acc1, 0, 0, 0);
            __builtin_amdgcn_s_setprio(0);

            // rotate
            Ah = nAh; Al = nAl;
            bh0 = nbh0; bl0 = nbl0; bh1 = nbh1; bl1 = nbl1;
        }
        #undef AFRAG
        #undef BPTR

        // epilogue: surrogate distance + running argmin (ascending codeword).
        // hn[] read from global (broadcast addresses, L1-hot).
        const int cwb = pan * 32 + 4 * g;
        #pragma unroll
        for (int r = 0; r < 16; ++r) {
            const int cw = cwb + (r & 3) + 8 * (r >> 2);
            const float hc = hn[cw];
            float s0 = fmaf(-2.0f, acc0[r], hc);
            if (s0 < minv[0]) { minv[0] = s0; mini[0] = cw; }
            float s1 = fmaf(-2.0f, acc1[r], hc);
            if (s1 < minv[1]) { minv[1] = s1; mini[1] = cw; }
        }
    }

    // combine the two g-halves in-register (tie -> lower index)
    #pragma unroll
    for (int qg = 0; qg < 2; ++qg) {
        float ov = __shfl_xor(minv[qg], 32);
        int oi = __shfl_xor(mini[qg], 32);
        if (ov < minv[qg] || (ov == minv[qg] && oi < mini[qg])) {
            minv[qg] = ov; mini[qg] = oi;
        }
    }

    // qF is now dead -> overlay cross-wave scratch + final indices on it
    __syncthreads();
    float* sm   = reinterpret_cast<float*>(qF);          // [8][64]
    int*   si   = reinterpret_cast<int*>(qF) + 512;      // [8][64]
    int*   fidx = reinterpret_cast<int*>(qF) + 1024;     // [64]
    if (g == 0) {
        #pragma unroll
        for (int qg = 0; qg < 2; ++qg) {
            sm[wave * 64 + qg * 32 + m31] = minv[qg];
            si[wave * 64 + qg * 32 + m31] = mini[qg];
        }
    }
    __syncthreads();

    // cross-wave reduce (wave order = ascending codeword blocks), then
    // block loss partial = sum of selected surrogate distances.
    if (tid < 64) {
        float bv = sm[tid]; int bi = si[tid];
        #pragma unroll
        for (int w = 1; w < 8; ++w) {
            float v = sm[w * 64 + tid]; int ii = si[w * 64 + tid];
            if (v < bv || (v == bv && ii < bi)) { bv = v; bi = ii; }
        }
        out_idx_f[qbase + tid] = (float)bi;
        fidx[tid] = bi;
        float vs = bv;
        #pragma unroll
        for (int d = 32; d; d >>= 1) vs += __shfl_xor(vs, d);
        if (tid == 0) part_s[blockIdx.x] = vs;
    }
    __syncthreads();

    // fused gather: z_q rows for this block's 64 queries (coalesced, cb L2-hot)
    const float4* cb4 = reinterpret_cast<const float4*>(cb);
    float4* zq4 = reinterpret_cast<float4*>(zq) + (size_t)qbase * 64;
    #pragma unroll
    for (int it = 0; it < 8; ++it) {
        const int j = it * 512 + tid;               // 4096 float4 units
        const int q = j >> 6, seg = j & 63;
        const int cw = fidx[q];
        zq4[j] = cb4[(size_t)cw * 64 + seg];
    }
}

// ---------------------------------------------------------------------------
// Kernel 3: reduce partials -> loss = (sum_s + sum_x2) / (B*N*D)
// ---------------------------------------------------------------------------
__global__ void vq_finish(const float* __restrict__ part_s,
                          const float* __restrict__ part_x2,
                          float* __restrict__ out_loss) {
    float s = 0.0f;
    for (int i = threadIdx.x; i < 1024; i += 256) s += part_s[i];
    for (int i = threadIdx.x; i < 8192; i += 256) s += part_x2[i];
    #pragma unroll
    for (int d = 32; d; d >>= 1) s += __shfl_xor(s, d);
    __shared__ float ps[4];
    if ((threadIdx.x & 63) == 0) ps[threadIdx.x >> 6] = s;
    __syncthreads();
    if (threadIdx.x == 0)
        *out_loss = (ps[0] + ps[1] + ps[2] + ps[3]) * (1.0f / 16777216.0f);
}

extern "C" void kernel_launch(void* const* d_in, const int* in_sizes, int n_in,
                              void* d_out, int out_size, void* d_ws, size_t ws_size,
                              hipStream_t stream) {
    const float* z_e = (const float*)d_in[0];
    const float* cb  = (const float*)d_in[1];

    float* out   = (float*)d_out;
    float* zq    = out;
    float* oidx  = out + (size_t)MTOT * KDIM;
    float* oloss = out + (size_t)MTOT * KDIM + MTOT;

    char* ws = (char*)d_ws;
    _Float16* cbF  = (_Float16*)ws;                              // 1 MB
    float* hn      = (float*)(ws + 1024 * 1024);                 // 4 KB
    float* part_s  = (float*)(ws + 1024 * 1024 + 4096);          // 4 KB
    float* part_x2 = (float*)(ws + 1024 * 1024 + 8192);          // 32 KB

    vq_prep<<<128, 256, 0, stream>>>(cb, cbF, hn);
    vq_main<<<MTOT / 64, 512, 0, stream>>>(z_e, cbF, hn, cb, oidx, zq,
                                           part_s, part_x2);
    vq_finish<<<1, 256, 0, stream>>>(part_s, part_x2, oloss);
}